// Round 3
// baseline (233.881 us; speedup 1.0000x reference)
//
#include <hip/hip_runtime.h>

typedef unsigned short ushort_t;
typedef __attribute__((ext_vector_type(8))) short short8;
typedef __attribute__((ext_vector_type(4))) float f32x4;

#define BM 128
#define BN 128

// ---------- helpers ----------

__device__ __forceinline__ ushort_t f32_to_bf16_rne(float x) {
    unsigned u = __builtin_bit_cast(unsigned, x);
    unsigned r = u + 0x7fffu + ((u >> 16) & 1u);
    return (ushort_t)(r >> 16);
}

__device__ __forceinline__ float bf16_to_f32(ushort_t h) {
    unsigned u = ((unsigned)h) << 16;
    return __builtin_bit_cast(float, u);
}

// ---------- prep: fp32 X -> bf16 Xb, and sq[i] = ||Xb_i||^2 (from rounded values) ----------

__global__ void krr_prep(const float* __restrict__ X, ushort_t* __restrict__ Xb,
                         float* __restrict__ sq, int D) {
    const int row = blockIdx.x;
    const int t = threadIdx.x;
    float s = 0.f;
    for (int k = t; k < D; k += blockDim.x) {
        float x = X[(size_t)row * D + k];
        ushort_t hb = f32_to_bf16_rne(x);
        Xb[(size_t)row * D + k] = hb;
        float xf = bf16_to_f32(hb);
        s = fmaf(xf, xf, s);
    }
    #pragma unroll
    for (int off = 32; off > 0; off >>= 1) s += __shfl_xor(s, off, 64);
    __shared__ float red[4];
    const int lane = t & 63, w = t >> 6;
    if (lane == 0) red[w] = s;
    __syncthreads();
    if (t == 0) sq[row] = red[0] + red[1] + red[2] + red[3];
}

// ---------- main fused kernel: no LDS, no barriers; fragments direct from L2 ----------

__global__ __launch_bounds__(256, 2) void krr_l2(
    const ushort_t* __restrict__ Xb, const float* __restrict__ sq,
    const float* __restrict__ alpha, float* __restrict__ out,
    int N, int D)
{
    const int tid  = threadIdx.x;
    const int lane = tid & 63;
    const int w    = tid >> 6;          // 4 waves, 2x2
    const int wr   = (w >> 1) * 64;
    const int wc   = (w & 1) * 64;

    // bijective XCD-aware swizzle (nwg = 4096, % 8 == 0)
    const int nbx = gridDim.x;
    const int nwg = gridDim.x * gridDim.y;
    int linear = blockIdx.y * nbx + blockIdx.x;
    int cpx = nwg >> 3;
    int swz = (linear & 7) * cpx + (linear >> 3);
    const int rowBase = (swz / nbx) * BM;
    const int colBase = (swz % nbx) * BN;

    f32x4 acc[4][4];
    #pragma unroll
    for (int m = 0; m < 4; ++m)
        #pragma unroll
        for (int n = 0; n < 4; ++n)
            acc[m][n] = (f32x4){0.f, 0.f, 0.f, 0.f};

    // fragment base addresses: row = base + frag*16 + (lane&15), k-chunk = (lane>>4)*8
    const ushort_t* Abase = Xb + (size_t)(rowBase + wr + (lane & 15)) * D + ((lane >> 4) * 8);
    const ushort_t* Bbase = Xb + (size_t)(colBase + wc + (lane & 15)) * D + ((lane >> 4) * 8);
    const size_t rstep = (size_t)16 * D;   // 16 rows per fragment step

    const int nks = D >> 5;   // K-steps of 32

    short8 a0[4], b0[4];
    #pragma unroll
    for (int m = 0; m < 4; ++m) a0[m] = *reinterpret_cast<const short8*>(Abase + m * rstep);
    #pragma unroll
    for (int n = 0; n < 4; ++n) b0[n] = *reinterpret_cast<const short8*>(Bbase + n * rstep);

    for (int ks = 0; ks < nks; ++ks) {
        if (ks + 1 < nks) {
            const ushort_t* An = Abase + (ks + 1) * 32;
            const ushort_t* Bn = Bbase + (ks + 1) * 32;
            short8 a1[4], b1[4];
            #pragma unroll
            for (int m = 0; m < 4; ++m) a1[m] = *reinterpret_cast<const short8*>(An + m * rstep);
            #pragma unroll
            for (int n = 0; n < 4; ++n) b1[n] = *reinterpret_cast<const short8*>(Bn + n * rstep);
            #pragma unroll
            for (int m = 0; m < 4; ++m)
                #pragma unroll
                for (int n = 0; n < 4; ++n)
                    acc[m][n] = __builtin_amdgcn_mfma_f32_16x16x32_bf16(
                        a0[m], b0[n], acc[m][n], 0, 0, 0);
            #pragma unroll
            for (int m = 0; m < 4; ++m) a0[m] = a1[m];
            #pragma unroll
            for (int n = 0; n < 4; ++n) b0[n] = b1[n];
        } else {
            #pragma unroll
            for (int m = 0; m < 4; ++m)
                #pragma unroll
                for (int n = 0; n < 4; ++n)
                    acc[m][n] = __builtin_amdgcn_mfma_f32_16x16x32_bf16(
                        a0[m], b0[n], acc[m][n], 0, 0, 0);
        }
    }

    // ---- fused epilogue: d2 -> exp -> *alpha -> 16-lane col reduce -> atomicAdd ----
    float sqc[4], alc[4];
    #pragma unroll
    for (int n = 0; n < 4; ++n) {
        int c = colBase + wc + n * 16 + (lane & 15);
        sqc[n] = sq[c];
        alc[n] = alpha[c];
    }
    const int g = lane >> 4;
    #pragma unroll
    for (int m = 0; m < 4; ++m) {
        int r0 = rowBase + wr + m * 16 + g * 4;
        #pragma unroll
        for (int reg = 0; reg < 4; ++reg) {
            float sqr = sq[r0 + reg];
            float s = 0.f;
            #pragma unroll
            for (int n = 0; n < 4; ++n) {
                float d2 = sqr + sqc[n] - 2.0f * acc[m][n][reg];
                d2 = fmaxf(d2, 0.f);
                s += __expf(-d2) * alc[n];
            }
            s += __shfl_xor(s, 1, 16);
            s += __shfl_xor(s, 2, 16);
            s += __shfl_xor(s, 4, 16);
            s += __shfl_xor(s, 8, 16);
            if ((lane & 15) == 0) atomicAdd(&out[r0 + reg], s);
        }
    }
}

// ---------- fallback: honest fp32, slow ----------

__global__ void krr_naive(const float* __restrict__ X, const float* __restrict__ alpha,
                          float* __restrict__ out, int N, int D) {
    __shared__ float xi[256];
    const int i = blockIdx.x;
    const int t = threadIdx.x;
    for (int k = t; k < D; k += blockDim.x) xi[k] = X[(size_t)i * D + k];
    __syncthreads();
    float s = 0.f;
    for (int j = t; j < N; j += blockDim.x) {
        float d2 = 0.f;
        const float* xj = &X[(size_t)j * D];
        for (int k = 0; k < D; ++k) {
            float d = xi[k] - xj[k];
            d2 = fmaf(d, d, d2);
        }
        s += __expf(-fmaxf(d2, 0.f)) * alpha[j];
    }
    #pragma unroll
    for (int off = 32; off > 0; off >>= 1) s += __shfl_xor(s, off, 64);
    __shared__ float red[4];
    const int lane = t & 63, w = t >> 6;
    if (lane == 0) red[w] = s;
    __syncthreads();
    if (t == 0) out[i] = red[0] + red[1] + red[2] + red[3];
}

// ---------- launch ----------

extern "C" void kernel_launch(void* const* d_in, const int* in_sizes, int n_in,
                              void* d_out, int out_size, void* d_ws, size_t ws_size,
                              hipStream_t stream) {
    const float* X     = (const float*)d_in[0];
    const float* alpha = (const float*)d_in[1];
    float* out = (float*)d_out;

    const int N = in_sizes[1];           // 8192
    const int D = in_sizes[0] / N;       // 256

    size_t xb_bytes = (size_t)N * D * sizeof(ushort_t);
    size_t need     = xb_bytes + (size_t)N * sizeof(float);

    hipMemsetAsync(d_out, 0, (size_t)out_size * sizeof(float), stream);

    bool shapes_ok = (D % 32) == 0 && (N % BM) == 0 && (N % BN) == 0 &&
                     (((N / BM) * (N / BN)) % 8) == 0;

    if (ws_size >= need && shapes_ok) {
        ushort_t* Xb = (ushort_t*)d_ws;
        float*    sq = (float*)((char*)d_ws + xb_bytes);
        krr_prep<<<N, 256, 0, stream>>>(X, Xb, sq, D);
        dim3 grid(N / BN, N / BM);
        krr_l2<<<grid, 256, 0, stream>>>(Xb, sq, alpha, out, N, D);
    } else {
        krr_naive<<<N, 256, 0, stream>>>(X, alpha, out, N, D);
    }
}

// Round 4
// 74.142 us; speedup vs baseline: 3.1545x; 3.1545x over previous
//
#include <hip/hip_runtime.h>

typedef unsigned short ushort_t;
typedef __attribute__((ext_vector_type(8))) short short8;
typedef __attribute__((ext_vector_type(4))) float f32x4;

#define BM 128
#define BN 128
#define BK 64

// ---------- helpers ----------

__device__ __forceinline__ ushort_t f32_to_bf16_rne(float x) {
    unsigned u = __builtin_bit_cast(unsigned, x);
    unsigned r = u + 0x7fffu + ((u >> 16) & 1u);
    return (ushort_t)(r >> 16);
}

__device__ __forceinline__ float bf16_to_f32(ushort_t h) {
    unsigned u = ((unsigned)h) << 16;
    return __builtin_bit_cast(float, u);
}

__device__ __forceinline__ void gload_lds16(const void* g, void* l) {
    __builtin_amdgcn_global_load_lds(
        (const __attribute__((address_space(1))) void*)g,
        (__attribute__((address_space(3))) void*)l,
        16, 0, 0);
}

// ---------- prep: fp32 X -> bf16 Xb, sq[i] = ||Xb_i||^2, zero out[i] ----------

__global__ void krr_prep(const float* __restrict__ X, ushort_t* __restrict__ Xb,
                         float* __restrict__ sq, float* __restrict__ out, int D) {
    const int row = blockIdx.x;
    const int t = threadIdx.x;
    float s = 0.f;
    for (int k = t; k < D; k += blockDim.x) {
        float x = X[(size_t)row * D + k];
        ushort_t hb = f32_to_bf16_rne(x);
        Xb[(size_t)row * D + k] = hb;
        float xf = bf16_to_f32(hb);
        s = fmaf(xf, xf, s);
    }
    #pragma unroll
    for (int off = 32; off > 0; off >>= 1) s += __shfl_xor(s, off, 64);
    __shared__ float red[4];
    const int lane = t & 63, w = t >> 6;
    if (lane == 0) red[w] = s;
    __syncthreads();
    if (t == 0) {
        sq[row]  = red[0] + red[1] + red[2] + red[3];
        out[row] = 0.f;
    }
}

// ---------- symmetric fused kernel: upper-triangular tiles only ----------
// block (ti,tj), ti<=tj: S = Xb[I].Xb[J]^T; K = exp(-d2)
//   row path (always):       out[I] += K  @ alpha[J]
//   col path (ti!=tj only):  out[J] += K^T@ alpha[I]

__global__ __launch_bounds__(256, 2) void krr_sym(
    const ushort_t* __restrict__ Xb, const float* __restrict__ sq,
    const float* __restrict__ alpha, float* __restrict__ out,
    int N, int D)
{
    __shared__ __align__(16) ushort_t As[BM * BK];
    __shared__ __align__(16) ushort_t Bs[BN * BK];

    const int tid  = threadIdx.x;
    const int lane = tid & 63;
    const int w    = tid >> 6;          // 4 waves, 2x2
    const int wr   = (w >> 1) * 64;
    const int wc   = (w & 1) * 64;

    // bijective XCD-aware swizzle (m204 general form)
    const int nwg = gridDim.x;
    const int linear = blockIdx.x;
    const int q = nwg >> 3, r8 = nwg & 7;
    const int xcd = linear & 7, rest = linear >> 3;
    const int swz = (xcd < r8 ? xcd * (q + 1) : r8 * (q + 1) + (xcd - r8) * q) + rest;

    // triangular decode: swz -> (ti, tj), ti <= tj
    const int T = N / BM;
    float Tf = (float)T + 0.5f;
    int ti = (int)(Tf - sqrtf(Tf * Tf - 2.0f * (float)swz));
    if (ti < 0) ti = 0;
    #define TRI_START(i) ((i) * T - ((i) * ((i) - 1)) / 2)
    while (TRI_START(ti + 1) <= swz) ++ti;
    while (TRI_START(ti) > swz) --ti;
    const int tj = ti + (swz - TRI_START(ti));
    #undef TRI_START
    const int rowBase = ti * BM;
    const int colBase = tj * BN;
    const bool offdiag = (ti != tj);

    f32x4 acc[4][4];
    #pragma unroll
    for (int m = 0; m < 4; ++m)
        #pragma unroll
        for (int n = 0; n < 4; ++n)
            acc[m][n] = (f32x4){0.f, 0.f, 0.f, 0.f};

    const int nkt = D / BK;
    for (int kt = 0; kt < nkt; ++kt) {
        // ---- stage A and B tiles (linear LDS dest, pre-swizzled global source) ----
        #pragma unroll
        for (int it = 0; it < 4; ++it) {
            int chunk = it * 256 + tid;       // 0..1023 (16B chunks)
            int r   = chunk >> 3;             // tile row 0..127
            int c8  = chunk & 7;
            int c8s = c8 ^ (r & 7);
            size_t goffA = (size_t)(rowBase + r) * D + kt * BK + c8s * 8;
            size_t goffB = (size_t)(colBase + r) * D + kt * BK + c8s * 8;
            gload_lds16(&Xb[goffA], &As[chunk * 8]);
            gload_lds16(&Xb[goffB], &Bs[chunk * 8]);
        }
        __syncthreads();

        // ---- MFMA over two k=32 sub-steps ----
        #pragma unroll
        for (int ks = 0; ks < 2; ++ks) {
            short8 a[4], b[4];
            #pragma unroll
            for (int m = 0; m < 4; ++m) {
                int r   = wr + m * 16 + (lane & 15);
                int c8x = (ks * 4 + (lane >> 4)) ^ (r & 7);
                a[m] = *reinterpret_cast<const short8*>(&As[(r * 8 + c8x) * 8]);
            }
            #pragma unroll
            for (int n = 0; n < 4; ++n) {
                int r   = wc + n * 16 + (lane & 15);
                int c8x = (ks * 4 + (lane >> 4)) ^ (r & 7);
                b[n] = *reinterpret_cast<const short8*>(&Bs[(r * 8 + c8x) * 8]);
            }
            #pragma unroll
            for (int m = 0; m < 4; ++m)
                #pragma unroll
                for (int n = 0; n < 4; ++n)
                    acc[m][n] = __builtin_amdgcn_mfma_f32_16x16x32_bf16(
                        a[m], b[n], acc[m][n], 0, 0, 0);
        }
        __syncthreads();
    }

    // ---- fused epilogue ----
    float sqc[4], alc[4];
    #pragma unroll
    for (int n = 0; n < 4; ++n) {
        int c = colBase + wc + n * 16 + (lane & 15);
        sqc[n] = sq[c];
        alc[n] = alpha[c];
    }
    float csum[4] = {0.f, 0.f, 0.f, 0.f};
    const int g = lane >> 4;
    #pragma unroll
    for (int m = 0; m < 4; ++m) {
        int r0 = rowBase + wr + m * 16 + g * 4;
        #pragma unroll
        for (int reg = 0; reg < 4; ++reg) {
            float sqr = sq[r0 + reg];
            float ar  = alpha[r0 + reg];
            float s = 0.f;
            #pragma unroll
            for (int n = 0; n < 4; ++n) {
                float d2 = sqr + sqc[n] - 2.0f * acc[m][n][reg];
                d2 = fmaxf(d2, 0.f);
                float k = __expf(-d2);
                s += k * alc[n];
                csum[n] = fmaf(k, ar, csum[n]);
            }
            // row-sum across the 16 columns held by this 16-lane group
            s += __shfl_xor(s, 1, 16);
            s += __shfl_xor(s, 2, 16);
            s += __shfl_xor(s, 4, 16);
            s += __shfl_xor(s, 8, 16);
            if ((lane & 15) == 0) atomicAdd(&out[r0 + reg], s);
        }
    }
    if (offdiag) {
        // col-sum: reduce csum over the four 16-lane groups (same lane&15)
        #pragma unroll
        for (int n = 0; n < 4; ++n) {
            csum[n] += __shfl_xor(csum[n], 16, 64);
            csum[n] += __shfl_xor(csum[n], 32, 64);
            if (g == 0)
                atomicAdd(&out[colBase + wc + n * 16 + (lane & 15)], csum[n]);
        }
    }
}

// ---------- fallback: honest fp32, slow ----------

__global__ void krr_naive(const float* __restrict__ X, const float* __restrict__ alpha,
                          float* __restrict__ out, int N, int D) {
    __shared__ float xi[256];
    const int i = blockIdx.x;
    const int t = threadIdx.x;
    for (int k = t; k < D; k += blockDim.x) xi[k] = X[(size_t)i * D + k];
    __syncthreads();
    float s = 0.f;
    for (int j = t; j < N; j += blockDim.x) {
        float d2 = 0.f;
        const float* xj = &X[(size_t)j * D];
        for (int k = 0; k < D; ++k) {
            float d = xi[k] - xj[k];
            d2 = fmaf(d, d, d2);
        }
        s += __expf(-fmaxf(d2, 0.f)) * alpha[j];
    }
    #pragma unroll
    for (int off = 32; off > 0; off >>= 1) s += __shfl_xor(s, off, 64);
    __shared__ float red[4];
    const int lane = t & 63, w = t >> 6;
    if (lane == 0) red[w] = s;
    __syncthreads();
    if (t == 0) out[i] = red[0] + red[1] + red[2] + red[3];
}

// ---------- launch ----------

extern "C" void kernel_launch(void* const* d_in, const int* in_sizes, int n_in,
                              void* d_out, int out_size, void* d_ws, size_t ws_size,
                              hipStream_t stream) {
    const float* X     = (const float*)d_in[0];
    const float* alpha = (const float*)d_in[1];
    float* out = (float*)d_out;

    const int N = in_sizes[1];           // 8192
    const int D = in_sizes[0] / N;       // 256

    size_t xb_bytes = (size_t)N * D * sizeof(ushort_t);
    size_t need     = xb_bytes + (size_t)N * sizeof(float);

    bool shapes_ok = (D % BK) == 0 && (N % BM) == 0 && (BM == BN) && (N == out_size);

    if (ws_size >= need && shapes_ok) {
        ushort_t* Xb = (ushort_t*)d_ws;
        float*    sq = (float*)((char*)d_ws + xb_bytes);
        krr_prep<<<N, 256, 0, stream>>>(X, Xb, sq, out, D);
        const int T = N / BM;
        const int ntiles = T * (T + 1) / 2;   // 2080 for N=8192
        krr_sym<<<ntiles, 256, 0, stream>>>(Xb, sq, alpha, out, N, D);
    } else {
        hipMemsetAsync(d_out, 0, (size_t)out_size * sizeof(float), stream);
        krr_naive<<<N, 256, 0, stream>>>(X, alpha, out, N, D);
    }
}